// Round 1
// baseline (1094.461 us; speedup 1.0000x reference)
//
#include <hip/hip_runtime.h>

// Problem constants (match reference.py)
#define N_NODES 200000
#define K 16
#define D 8

// One thread per (node, half): thread computes out[n, h*4 .. h*4+3].
// W viewed as float4[N][128][2]; thread (n,h) reads W4[n][f][h] for f=0..127.
// W is read exactly once overall -> memory-bound on ~819 MB of W traffic.
__global__ __launch_bounds__(256) void node_linear_sigmoid(
    const float* __restrict__ values,   // [N, D] f32
    const int*   __restrict__ nbr,      // [N, K] int
    const float* __restrict__ W,        // [N, K*D, D] f32
    const float* __restrict__ bias,     // [N, D] f32
    float*       __restrict__ out)      // [N, D] f32
{
    const int tid = blockIdx.x * blockDim.x + threadIdx.x;
    if (tid >= N_NODES * 2) return;
    const int n = tid >> 1;
    const int h = tid & 1;  // which float4 of the 8 outputs

    const float4* __restrict__ W4 = (const float4*)W + (size_t)n * 256 + h; // stride-2 rows
    const int*    __restrict__ my_nbr = nbr + n * K;

    float4 acc = make_float4(0.f, 0.f, 0.f, 0.f);

    #pragma unroll 2
    for (int k = 0; k < K; ++k) {
        const int s = my_nbr[k];
        const float4* __restrict__ v4 = (const float4*)(values + (size_t)s * D);
        const float4 v0 = v4[0];
        const float4 v1 = v4[1];
        const float g[8] = {v0.x, v0.y, v0.z, v0.w, v1.x, v1.y, v1.z, v1.w};
        const float4* __restrict__ Wk = W4 + k * 16;  // 8 rows * 2 float4/row
        #pragma unroll
        for (int j = 0; j < 8; ++j) {
            const float4 w = Wk[(size_t)j * 2];
            acc.x = fmaf(g[j], w.x, acc.x);
            acc.y = fmaf(g[j], w.y, acc.y);
            acc.z = fmaf(g[j], w.z, acc.z);
            acc.w = fmaf(g[j], w.w, acc.w);
        }
    }

    const float4 bb = *((const float4*)(bias + (size_t)n * D) + h);
    acc.x += bb.x; acc.y += bb.y; acc.z += bb.z; acc.w += bb.w;

    float4 r;
    r.x = 1.f / (1.f + __expf(-acc.x));
    r.y = 1.f / (1.f + __expf(-acc.y));
    r.z = 1.f / (1.f + __expf(-acc.z));
    r.w = 1.f / (1.f + __expf(-acc.w));

    *((float4*)(out + (size_t)n * D) + h) = r;
}

extern "C" void kernel_launch(void* const* d_in, const int* in_sizes, int n_in,
                              void* d_out, int out_size, void* d_ws, size_t ws_size,
                              hipStream_t stream) {
    const float* values = (const float*)d_in[0];  // [N, D]
    const int*   nbr    = (const int*)d_in[1];    // [N, K]
    const float* W      = (const float*)d_in[2];  // [N, K*D, D]
    const float* bias   = (const float*)d_in[3];  // [N, D]
    float*       out    = (float*)d_out;          // [N, D]

    const int total_threads = N_NODES * 2;
    const int block = 256;
    const int grid = (total_threads + block - 1) / block;
    node_linear_sigmoid<<<grid, block, 0, stream>>>(values, nbr, W, bias, out);
}

// Round 2
// 1013.972 us; speedup vs baseline: 1.0794x; 1.0794x over previous
//
#include <hip/hip_runtime.h>

// Problem constants (match reference.py)
#define N_NODES 200000
#define K 16
#define D 8

typedef float vfloat4 __attribute__((ext_vector_type(4)));

// One wave (64 lanes) per node.
//  Phase 1: 16 neighbor rows (128 floats) staged into LDS, float2 per lane.
//  Phase 2: W[n] (4 KB) read as 4 x 1KB fully-coalesced nontemporal dwordx4;
//           lane l at step t holds W[f=32t+(l>>1)][4h..4h+3], h=l&1.
//  Reduce:  5-step shfl_xor butterfly over same-parity lanes -> out halves.
__global__ __launch_bounds__(256) void node_linear_sigmoid_wave(
    const float* __restrict__ values,   // [N, D] f32
    const int*   __restrict__ nbr,      // [N, K] int32
    const float* __restrict__ W,        // [N, K*D, D] f32
    const float* __restrict__ bias,     // [N, D] f32
    float*       __restrict__ out)      // [N, D] f32
{
    __shared__ float g[4][128];         // per-wave gathered features
    const int lane = threadIdx.x & 63;
    const int wave = threadIdx.x >> 6;
    const int n = blockIdx.x * 4 + wave;   // grid covers exactly N_NODES

    // ---- Phase 1: gather. lane l loads values[nbr[n][l>>2]][(l&3)*2 .. +1]
    const int k = lane >> 2;
    const int c = lane & 3;
    const int s = nbr[n * K + k];
    const float2 v = *(const float2*)(values + (size_t)s * D + c * 2);
    *(float2*)&g[wave][2 * lane] = v;    // g[f]: f = k*8 + c*2 (+1) = 2*lane (+1)
    __syncthreads();

    // ---- Phase 2: W sweep, perfectly coalesced.
    const vfloat4* __restrict__ W4 = (const vfloat4*)W + (size_t)n * 256;
    const int half = lane >> 1;
    vfloat4 p = {0.f, 0.f, 0.f, 0.f};
    #pragma unroll
    for (int t = 0; t < 4; ++t) {
        const vfloat4 w4 = __builtin_nontemporal_load(W4 + t * 64 + lane);
        const float gf = g[wave][32 * t + half];
        p.x = fmaf(gf, w4.x, p.x);
        p.y = fmaf(gf, w4.y, p.y);
        p.z = fmaf(gf, w4.z, p.z);
        p.w = fmaf(gf, w4.w, p.w);
    }

    // ---- Butterfly reduction over lanes of same parity (h = lane&1 fixed).
    #pragma unroll
    for (int m = 2; m <= 32; m <<= 1) {
        p.x += __shfl_xor(p.x, m, 64);
        p.y += __shfl_xor(p.y, m, 64);
        p.z += __shfl_xor(p.z, m, 64);
        p.w += __shfl_xor(p.w, m, 64);
    }

    // lane 0 -> out[n][0..3], lane 1 -> out[n][4..7]
    if (lane < 2) {
        const vfloat4 bb = ((const vfloat4*)(bias + (size_t)n * D))[lane];
        vfloat4 r;
        r.x = 1.f / (1.f + __expf(-(p.x + bb.x)));
        r.y = 1.f / (1.f + __expf(-(p.y + bb.y)));
        r.z = 1.f / (1.f + __expf(-(p.z + bb.z)));
        r.w = 1.f / (1.f + __expf(-(p.w + bb.w)));
        ((vfloat4*)(out + (size_t)n * D))[lane] = r;
    }
}

extern "C" void kernel_launch(void* const* d_in, const int* in_sizes, int n_in,
                              void* d_out, int out_size, void* d_ws, size_t ws_size,
                              hipStream_t stream) {
    const float* values = (const float*)d_in[0];  // [N, D]
    const int*   nbr    = (const int*)d_in[1];    // [N, K]
    const float* W      = (const float*)d_in[2];  // [N, K*D, D]
    const float* bias   = (const float*)d_in[3];  // [N, D]
    float*       out    = (float*)d_out;          // [N, D]

    const int block = 256;                 // 4 waves -> 4 nodes per block
    const int grid = N_NODES / 4;          // 200000 / 4 = 50000, exact
    node_linear_sigmoid_wave<<<grid, block, 0, stream>>>(values, nbr, W, bias, out);
}